// Round 7
// baseline (179.416 us; speedup 1.0000x reference)
//
#include <hip/hip_runtime.h>
#include <math.h>

// ---------------------------------------------------------------------------
// KAN-Conv CIFAR net on gfx950, round 12.
// Model reconciling r5-r11: per wave-tap, FMA = 56*GO SIMD-cyc vs act-LDS
// ~96 CU-cyc shared by 4 SIMDs -> GO=4 is LDS-bound 1.7x (r5/r8), GO=8 is
// VALU-bound but r7 ran it at 2 waves/SIMD -> latency-starved null. This
// round combines GO=8 WITH 4 waves/SIMD on L2/L3:
//  - L2: GO=8, VS=4 (24KB act), FS=8, NT=256, grid 1024, bounds(256,4)
//        -> 4 blocks/CU = 16 waves/CU.
//  - L3: GO=8, VS=2, OS=2 (27KB act), FS=16, NT=256, grid 1024 -> 4/CU.
//  - weights stay GLOBAL (VMEM pipe; LDS reserved for acts).
//  - FS*PPB=128 -> fh-partials are in-wave: shfl_xor butterfly + one 8KB
//    LDS round across the 2 waves per og-group (old NT*GO*16 buffer would
//    not fit the 4-block LDS budget).
// L1 + linear are r11-verbatim (L1 WLDS + inline w2/w3 prep).
// ---------------------------------------------------------------------------

#define BATCH 256

struct W3 { float x, y, z; };   // packed 12-byte LDS record

__device__ __forceinline__ void bspline_basis(float x, float bs[6]) {
    const float h = 2.0f / 3.0f;
    float g[10];
#pragma unroll
    for (int i = 0; i < 10; ++i) g[i] = (float)(i - 3) * h - 1.0f;
    float b[9];
#pragma unroll
    for (int i = 0; i < 9; ++i) b[i] = (x >= g[i] && x < g[i + 1]) ? 1.0f : 0.0f;
#pragma unroll
    for (int j = 1; j <= 3; ++j) {
        const float inv_d = 1.0f / ((float)j * h);
#pragma unroll
        for (int i = 0; i + j < 9; ++i) {
            float left  = (x - g[i]) * inv_d;
            float right = (g[i + j + 1] - x) * inv_d;
            b[i] = left * b[i] + right * b[i + 1];
        }
    }
#pragma unroll
    for (int i = 0; i < 6; ++i) bs[i] = b[i];
}

// Fused: basis precompute (LDS) + KAN conv3x3(pad1) + maxpool2.
// x: [B,C,H,W]; wrec: [C*9, O, 8] fused (tap-major); out: [B,O,H/2,W/2].
// VS: vertical split of pooled rows across blocks. OS: output-channel split
// across blocks. FS: channel split within block.
// WLDS: build this layer's fused weights in LDS from raw (bw,sw,sc).
// PREP: first blocks also fuse the OTHER layers' weights to global.
template <int C, int O, int GO, int H, int W, int VS, int OS, int FS, int NT,
          int MINW, int WLDS, int PREP>
__global__ __launch_bounds__(NT, MINW) void kan_conv_pool(
        const float* __restrict__ x,
        const float* __restrict__ wrec,
        const float* __restrict__ rbw, const float* __restrict__ rsw, const float* __restrict__ rsc,
        const float* __restrict__ p2bw, const float* __restrict__ p2sw, const float* __restrict__ p2sc,
        const float* __restrict__ p3bw, const float* __restrict__ p3sw, const float* __restrict__ p3sc,
        float* __restrict__ w2dst, float* __restrict__ w3dst,
        float* __restrict__ out) {
    constexpr int PH = H / 2, PW = W / 2;
    constexpr int PR = PH / VS;            // pooled rows per block
    constexpr int R  = 2 * PR + 2;         // input tile rows (incl. halo)
    constexpr int TC = W + 2;              // input tile cols (incl. halo)
    constexpr int CP = TC / 2;             // cols per parity plane
    constexpr int F  = C * 9;
    constexpr int PPB = PR * PW;           // pooled pixels per block
    constexpr int OPB = O / OS;            // output channels per block
    constexpr int NOG = OPB / GO;
    constexpr int CS = C / FS;             // channels per f-slice
    constexpr int CPLANE = R * 2 * CP;     // records per channel plane
    constexpr int HALF = C * CPLANE;       // records in act arena
    static_assert(NT == NOG * FS * PPB, "thread mapping");
    static_assert(FS * CS == C, "channel split");
    static_assert(NOG * GO == OPB && OPB * OS == O, "o split");

    constexpr bool WAVE_RED = (FS > 1) && (FS * PPB == 128) && (NOG == 2) && (NT == 256);
    constexpr int ACT_BYTES = HALF * 28;
    constexpr int RED_BYTES = (FS > 1) ? (WAVE_RED ? GO * (NT / 64) * PPB * 16
                                                   : NT * GO * 16) : 0;
    constexpr int ARENA = ACT_BYTES > RED_BYTES ? ACT_BYTES : RED_BYTES;
    static_assert(RED_BYTES <= ARENA, "red fits");
    __shared__ alignas(16) unsigned char s_mem[ARENA];
    float4* s_lo = (float4*)s_mem;
    W3*     s_hi = (W3*)(s_mem + (size_t)HALF * 16);
    constexpr int NWR = WLDS ? O * F : 1;
    __shared__ float4 s_wlo[NWR];
    __shared__ W3     s_whi[NWR];

    const int tid = threadIdx.x;
    const int bid = blockIdx.x;

    // ---- Inline prep of other layers' fused weights (first blocks only).
    if (PREP) {
        int i = bid * NT + tid;
        if (i < 5760) {
            const float *bw, *sw, *sc;
            float* dst;
            int j, OO, FF;
            if (i < 1152) { bw = p2bw; sw = p2sw; sc = p2sc; dst = w2dst; j = i;        OO = 16; FF = 72;  }
            else          { bw = p3bw; sw = p3sw; sc = p3sc; dst = w3dst; j = i - 1152; OO = 32; FF = 144; }
            int o = j / FF, fi = j % FF;   // input [O,F] row-major -> tap-major out
            float s = sc[j];
            float4* dq = (float4*)(dst + (size_t)(fi * OO + o) * 8);
            dq[0] = make_float4(bw[j], sw[j * 6 + 0] * s, sw[j * 6 + 1] * s, sw[j * 6 + 2] * s);
            dq[1] = make_float4(sw[j * 6 + 3] * s, sw[j * 6 + 4] * s, sw[j * 6 + 5] * s, 0.0f);
        }
    }

    // ---- Own-layer fused weights into LDS (tap-major r = f*O + o).
    if (WLDS) {
        for (int j = tid; j < O * F; j += NT) {
            int o = j / F, fi = j % F;
            float s = rsc[j];
            int r = fi * O + o;
            s_wlo[r] = make_float4(rbw[j], rsw[j * 6 + 0] * s, rsw[j * 6 + 1] * s, rsw[j * 6 + 2] * s);
            W3 t; t.x = rsw[j * 6 + 3] * s; t.y = rsw[j * 6 + 4] * s; t.z = rsw[j * 6 + 5] * s;
            s_whi[r] = t;
        }
    }

    const int b   = bid / (VS * OS);
    const int rem = bid % (VS * OS);
    const int v   = rem / OS;
    const int osb = rem % OS;
    const int r0 = v * (2 * PR) - 1;       // global row of tile row 0

    // ---- Stage: zero-padded x -> [silu, b0..b5] records in LDS
    const float* xb = x + (size_t)b * C * H * W;
    for (int i = tid; i < C * R * TC; i += NT) {
        int cc  = i / (R * TC);
        int rr  = (i / TC) % R;
        int col = i % TC;
        int gr = r0 + rr, gc = col - 1;
        float val = 0.0f;
        if ((unsigned)gr < (unsigned)H && (unsigned)gc < (unsigned)W)
            val = xb[(cc * H + gr) * W + gc];
        float silu = val / (1.0f + __expf(-val));
        float bs[6];
        bspline_basis(val, bs);
        int idx = ((cc * R + rr) * 2 + (col & 1)) * CP + (col >> 1);
        s_lo[idx] = make_float4(silu, bs[0], bs[1], bs[2]);
        W3 t; t.x = bs[3]; t.y = bs[4]; t.z = bs[5];
        s_hi[idx] = t;
    }
    __syncthreads();

    // ---- Thread mapping
    const int px = tid % PPB;
    const int fh = (tid / PPB) % FS;
    const int og = tid / (PPB * FS);
    const int phl = px / PW, pw = px % PW;
    const int o0 = osb * OPB + og * GO;

    float acc[GO][4];
#pragma unroll
    for (int g = 0; g < GO; ++g)
#pragma unroll
        for (int p = 0; p < 4; ++p) acc[g][p] = 0.f;

    const int pbase = (2 * phl) * (2 * CP) + pw;

#pragma unroll 1
    for (int cc = 0; cc < CS; ++cc) {
        const int c = fh * CS + cc;
        const float4* plo = s_lo + c * CPLANE;
        const W3*     phi = s_hi + c * CPLANE;
#pragma unroll 1
        for (int ky = 0; ky < 3; ++ky) {
#pragma unroll 1
            for (int kx = 0; kx < 3; ++kx) {
                const int f = c * 9 + ky * 3 + kx;
                float4 wl[GO];
                float  whx[GO], why[GO], whz[GO];
                if (WLDS) {
                    const int rb = f * O + o0;
#pragma unroll
                    for (int g = 0; g < GO; ++g) {
                        wl[g] = s_wlo[rb + g];
                        W3 t = s_whi[rb + g];
                        whx[g] = t.x; why[g] = t.y; whz[g] = t.z;
                    }
                } else {
                    const float4* wp = (const float4*)wrec + (size_t)(f * O + o0) * 2;
#pragma unroll
                    for (int g = 0; g < GO; ++g) {
                        wl[g] = wp[g * 2];
                        float4 hv = wp[g * 2 + 1];
                        whx[g] = hv.x; why[g] = hv.y; whz[g] = hv.z;
                    }
                }
#pragma unroll
                for (int dy = 0; dy < 2; ++dy) {
#pragma unroll
                    for (int dx = 0; dx < 2; ++dx) {
                        const int s = dx + kx;
                        const int off = pbase + ((dy + ky) * 2 + (s & 1)) * CP + (s >> 1);
                        float4 lo = plo[off];
                        W3     hi = phi[off];
#pragma unroll
                        for (int g = 0; g < GO; ++g) {
                            acc[g][dy * 2 + dx] +=
                                lo.x * wl[g].x + lo.y * wl[g].y + lo.z * wl[g].z +
                                lo.w * wl[g].w + hi.x * whx[g] + hi.y * why[g] +
                                hi.z * whz[g];
                        }
                    }
                }
            }
        }
    }

    if constexpr (WAVE_RED) {
        // fh groups sharing a wave: butterfly-reduce in registers (free of
        // the big LDS buffer); 2 waves per og-group -> one small LDS round.
#pragma unroll
        for (int g = 0; g < GO; ++g)
#pragma unroll
            for (int p = 0; p < 4; ++p) {
                if constexpr (PPB <= 8)  acc[g][p] += __shfl_xor(acc[g][p], 8);
                if constexpr (PPB <= 16) acc[g][p] += __shfl_xor(acc[g][p], 16);
                acc[g][p] += __shfl_xor(acc[g][p], 32);
            }
        float4* s_red = (float4*)s_mem;
        constexpr int NW = NT / 64;        // 4 waves
        const int wv = tid >> 6, lane = tid & 63;
        __syncthreads();                   // act reads done before overwrite
        if ((wv & 1) && lane < PPB) {
#pragma unroll
            for (int g = 0; g < GO; ++g)
                s_red[(g * NW + wv) * PPB + lane] =
                    make_float4(acc[g][0], acc[g][1], acc[g][2], acc[g][3]);
        }
        __syncthreads();
        if (!(wv & 1) && lane < PPB) {
            const int og_ = wv >> 1;
            const int oo = osb * OPB + og_ * GO;
            const int pl = lane / PW, pwl = lane % PW;
            const int pg = v * PR + pl;
#pragma unroll
            for (int g = 0; g < GO; ++g) {
                float4 t = s_red[(g * NW + wv + 1) * PPB + lane];
                float a0 = acc[g][0] + t.x, a1 = acc[g][1] + t.y;
                float a2 = acc[g][2] + t.z, a3 = acc[g][3] + t.w;
                float m = fmaxf(fmaxf(a0, a1), fmaxf(a2, a3));
                out[(((size_t)b * O + oo + g) * PH + pg) * PW + pwl] = m;
            }
        }
    } else if constexpr (FS > 1) {
        const int phg = v * PR + phl;
        float4* s_red = (float4*)s_mem;
        __syncthreads();                   // act reads done before overwrite
#pragma unroll
        for (int g = 0; g < GO; ++g)
            s_red[g * NT + tid] = make_float4(acc[g][0], acc[g][1], acc[g][2], acc[g][3]);
        __syncthreads();
        if (fh != 0) return;
#pragma unroll
        for (int fq = 1; fq < FS; ++fq)
#pragma unroll
            for (int g = 0; g < GO; ++g) {
                float4 t = s_red[g * NT + tid + fq * PPB];
                acc[g][0] += t.x; acc[g][1] += t.y; acc[g][2] += t.z; acc[g][3] += t.w;
            }
#pragma unroll
        for (int g = 0; g < GO; ++g) {
            float m = fmaxf(fmaxf(acc[g][0], acc[g][1]), fmaxf(acc[g][2], acc[g][3]));
            out[(((size_t)b * O + o0 + g) * PH + phg) * PW + pw] = m;
        }
    } else {
        const int phg = v * PR + phl;
#pragma unroll
        for (int g = 0; g < GO; ++g) {
            float m = fmaxf(fmaxf(acc[g][0], acc[g][1]), fmaxf(acc[g][2], acc[g][3]));
            out[(((size_t)b * O + o0 + g) * PH + phg) * PW + pw] = m;
        }
    }
}

// Wave-cooperative linear: block per n; h3[n] staged in LDS; wave wv owns
// outputs o = wv*25+i; w[o] rows read coalesced; shfl_xor reduce.
__global__ __launch_bounds__(256) void linear_coop(const float* __restrict__ h,
                                                   const float* __restrict__ w,
                                                   const float* __restrict__ bias,
                                                   float* __restrict__ out) {
    const int n = blockIdx.x;
    const int tid = threadIdx.x;
    const int lane = tid & 63;
    const int wv = tid >> 6;

    __shared__ float4 s_h[128];            // h3[n] as 128 float4
    if (tid < 128) s_h[tid] = ((const float4*)(h + (size_t)n * 512))[tid];
    __syncthreads();

    const float4 h0 = s_h[lane];
    const float4 h1 = s_h[lane + 64];

#pragma unroll 1
    for (int i = 0; i < 25; ++i) {
        const int o = wv * 25 + i;
        const float4* wr = (const float4*)(w + (size_t)o * 512);
        float4 w0 = wr[lane];
        float4 w1 = wr[lane + 64];
        float p = w0.x * h0.x + w0.y * h0.y + w0.z * h0.z + w0.w * h0.w
                + w1.x * h1.x + w1.y * h1.y + w1.z * h1.z + w1.w * h1.w;
        p += __shfl_xor(p, 32);
        p += __shfl_xor(p, 16);
        p += __shfl_xor(p, 8);
        p += __shfl_xor(p, 4);
        p += __shfl_xor(p, 2);
        p += __shfl_xor(p, 1);
        if (lane == 0) out[(size_t)n * 100 + o] = p + bias[o];
    }
}

extern "C" void kernel_launch(void* const* d_in, const int* in_sizes, int n_in,
                              void* d_out, int out_size, void* d_ws, size_t ws_size,
                              hipStream_t stream) {
    const float* x     = (const float*)d_in[0];
    const float* c1_bw = (const float*)d_in[1];
    const float* c1_sw = (const float*)d_in[2];
    const float* c1_sc = (const float*)d_in[3];
    const float* c2_bw = (const float*)d_in[4];
    const float* c2_sw = (const float*)d_in[5];
    const float* c2_sc = (const float*)d_in[6];
    const float* c3_bw = (const float*)d_in[7];
    const float* c3_sw = (const float*)d_in[8];
    const float* c3_sc = (const float*)d_in[9];
    const float* lin_w = (const float*)d_in[10];
    const float* lin_b = (const float*)d_in[11];
    float* out = (float*)d_out;

    float* ws = (float*)d_ws;
    float* h1 = ws;                 // 256*8*16*16  = 524288
    float* h2 = h1 + 524288;        // 256*16*8*8   = 262144
    float* h3 = h2 + 262144;        // 256*32*4*4   = 131072
    float* w2 = h3 + 131072;        // 1152*8 = 9216
    float* w3 = w2 + 9216;          // 4608*8 = 36864
    // total < 1M floats = 3.9 MB of workspace

    // L1: [256,3,32,32] -> [256,8,16,16]; GO=4, FS=3, NT=768, WLDS + inline
    // prep of w2/w3 (blocks 0..7). 512 blocks. (r11-verbatim)
    kan_conv_pool<3, 8, 4, 32, 32, 2, 1, 3, 768, 4, 1, 1><<<512, 768, 0, stream>>>(
        x, nullptr,
        c1_bw, c1_sw, c1_sc,
        c2_bw, c2_sw, c2_sc,
        c3_bw, c3_sw, c3_sc,
        w2, w3, h1);
    // L2: [256,8,16,16] -> [256,16,8,8]; GO=8, VS=4, FS=8, NT=256.
    // grid 1024 -> 4 blocks/CU (24KB act LDS), 16 waves/CU.
    kan_conv_pool<8, 16, 8, 16, 16, 4, 1, 8, 256, 4, 0, 0><<<1024, 256, 0, stream>>>(
        h1, w2,
        nullptr, nullptr, nullptr,
        nullptr, nullptr, nullptr,
        nullptr, nullptr, nullptr,
        nullptr, nullptr, h2);
    // L3: [256,16,8,8] -> [256,32,4,4]; GO=8, VS=2, OS=2, FS=16, NT=256.
    // grid 1024 -> 4 blocks/CU (27KB act LDS), 16 waves/CU.
    kan_conv_pool<16, 32, 8, 8, 8, 2, 2, 16, 256, 4, 0, 0><<<1024, 256, 0, stream>>>(
        h2, w3,
        nullptr, nullptr, nullptr,
        nullptr, nullptr, nullptr,
        nullptr, nullptr, nullptr,
        nullptr, nullptr, h3);
    // Linear: [256,512] @ [100,512]^T + b; block per n, coalesced w reads.
    linear_coop<<<256, 256, 0, stream>>>(h3, lin_w, lin_b, out);
}